// Round 13
// baseline (210.544 us; speedup 1.0000x reference)
//
#include <hip/hip_runtime.h>
#include <math.h>

#define N 16384
#define F 256
#define K_KEEP 8192

typedef float f32x4 __attribute__((ext_vector_type(4)));  // native vec for nontemporal builtins

// ---------------------------------------------------------------------------
// Kernel 1: y[i] = dot(X[i,:], p)/||p|| (fp64 accum), stored f32.
// One wave per row; lane l covers 4 consecutive floats.
// ---------------------------------------------------------------------------
__global__ __launch_bounds__(256) void score_kernel(const float* __restrict__ X,
                                                    const float* __restrict__ p,
                                                    float* __restrict__ y) {
    const int wave = threadIdx.x >> 6;
    const int lane = threadIdx.x & 63;
    const int row  = blockIdx.x * 4 + wave;

    const float4 pv = *reinterpret_cast<const float4*>(p + lane * 4);
    const float4 xv = *reinterpret_cast<const float4*>(X + (size_t)row * F + lane * 4);

    double pp = (double)pv.x * pv.x + (double)pv.y * pv.y +
                (double)pv.z * pv.z + (double)pv.w * pv.w;
    double xp = (double)xv.x * pv.x + (double)xv.y * pv.y +
                (double)xv.z * pv.z + (double)xv.w * pv.w;

    #pragma unroll
    for (int off = 32; off >= 1; off >>= 1) {
        pp += __shfl_down(pp, off, 64);
        xp += __shfl_down(xp, off, 64);
    }
    if (lane == 0) y[row] = (float)(xp / sqrt(pp));
}

// ---------------------------------------------------------------------------
// Kernel 2 (single block, 1024 threads): selection pipeline; y read from
// global exactly once into registers (16 contiguous values per thread).
// Emits ascending kept indices idx[] and colrank[N] (u16 rank among kept
// columns, 0xFFFF for dropped).
// ---------------------------------------------------------------------------
__global__ __launch_bounds__(1024) void select_emit_kernel(const float* __restrict__ y,
                                                           int* __restrict__ idx,
                                                           unsigned short* __restrict__ colrank) {
    __shared__ int hist[4096];
    __shared__ int part[1024];
    __shared__ int sc[256];
    __shared__ int bres[2];
    __shared__ float cand[1024];
    __shared__ int ccnt;
    __shared__ float sthr;
    __shared__ unsigned short fbw16[1024];
    const int t = threadIdx.x;

    #pragma unroll
    for (int q = 0; q < 4; ++q) hist[q * 1024 + t] = 0;
    if (t == 0) ccnt = 0;
    __syncthreads();

    // Phase A: one-shot register load of y[t*16 .. t*16+16) + histogram.
    float yv[16];
    const float4* __restrict__ y4 = reinterpret_cast<const float4*>(y + t * 16);
    #pragma unroll
    for (int q = 0; q < 4; ++q) {
        const float4 v = y4[q];
        yv[q * 4 + 0] = v.x; yv[q * 4 + 1] = v.y;
        yv[q * 4 + 2] = v.z; yv[q * 4 + 3] = v.w;
    }
    int bins[16];
    #pragma unroll
    for (int j = 0; j < 16; ++j) {
        const float v = fminf(fmaxf(yv[j] * 341.3333f + 2048.0f, 0.0f), 4095.0f);
        bins[j] = (int)v;
        atomicAdd(&hist[bins[j]], 1);
    }
    __syncthreads();

    // Phase B: chunk sums (4 bins/thread), inclusive scan, locate b*.
    part[t] = hist[t * 4] + hist[t * 4 + 1] + hist[t * 4 + 2] + hist[t * 4 + 3];
    __syncthreads();
    for (int off = 1; off < 1024; off <<= 1) {
        const int v = (t >= off) ? part[t - off] : 0;
        __syncthreads();
        part[t] += v;
        __syncthreads();
    }
    int acc = part[1023] - part[t];    // count strictly above chunk t's top bin
    int fbin = -1, fr = 0;
    #pragma unroll
    for (int q = 3; q >= 0; --q) {
        const int b = t * 4 + q;
        const int h = hist[b];
        if (fbin < 0 && acc <= K_KEEP - 1 && K_KEEP - 1 < acc + h) {
            fbin = b; fr = K_KEEP - acc;   // 1-based rank inside bin
        }
        acc += h;
    }
    if (fbin >= 0) { bres[0] = fbin; bres[1] = fr; }
    __syncthreads();
    const int bstar = bres[0];
    const int r     = bres[1];

    // Phase C: candidates from registers, exact in-bin select -> thr.
    #pragma unroll
    for (int j = 0; j < 16; ++j) {
        if (bins[j] == bstar) {
            const int pos = atomicAdd(&ccnt, 1);
            if (pos < 1024) cand[pos] = yv[j];
        }
    }
    __syncthreads();
    const int cc = (ccnt < 1024) ? ccnt : 1024;
    if (t < cc) {
        const float kk = cand[t];
        int g = 0;
        for (int j = 0; j < cc; ++j) g += (int)(cand[j] > kk);
        if (g == r - 1) sthr = kk;
    }
    __syncthreads();
    const float thr = sthr;

    // Phase D: per-thread contiguous 16-bit kept mask.
    unsigned int mask = 0;
    #pragma unroll
    for (int j = 0; j < 16; ++j) mask |= ((unsigned int)(yv[j] >= thr)) << j;
    fbw16[t] = (unsigned short)mask;
    __syncthreads();

    // Phase E: first 256 threads assemble u64 words, scan, emit idx+colrank.
    unsigned long long m = 0;
    if (t < 256) {
        m = (unsigned long long)fbw16[4 * t]
          | ((unsigned long long)fbw16[4 * t + 1] << 16)
          | ((unsigned long long)fbw16[4 * t + 2] << 32)
          | ((unsigned long long)fbw16[4 * t + 3] << 48);
        sc[t] = __popcll(m);
    }
    __syncthreads();
    for (int off = 1; off < 256; off <<= 1) {
        const int v = (t >= off && t < 256) ? sc[t - off] : 0;
        __syncthreads();
        if (t < 256) sc[t] += v;
        __syncthreads();
    }
    if (t < 256) {
        int base = sc[t] - __popcll(m);
        const int col = t * 64;
        for (int b = 0; b < 64; ++b) {
            if ((m >> b) & 1ull) {
                idx[base] = col + b;
                colrank[col + b] = (unsigned short)base;
                ++base;
            } else {
                colrank[col + b] = 0xFFFFu;
            }
        }
    }
}

// ---------------------------------------------------------------------------
// Kernel 3 (fused): blocks [0, 8192): sparse A-scatter — stream row
// A[idx[row],:] with nontemporal loads (~1% nonzero); for each nonzero in a
// kept column, store the value at outA[row, colrank[col]]. Output was
// memset-zeroed, so zeros need no writes; values are copied verbatim.
// Blocks [8192, +2048): X_pooled (one wave per kept row).
// ---------------------------------------------------------------------------
__global__ __launch_bounds__(256) void scatter_kernel(const float* __restrict__ A,
                                                      const float* __restrict__ X,
                                                      const float* __restrict__ y,
                                                      const int* __restrict__ idx,
                                                      const unsigned short* __restrict__ colrank,
                                                      float* __restrict__ outX,
                                                      float* __restrict__ outA) {
    const int t = threadIdx.x;

    if (blockIdx.x >= K_KEEP) {  // ---- xpool part ----
        const int k    = (blockIdx.x - K_KEEP) * 4 + (t >> 6);
        const int lane = t & 63;
        const int src  = idx[k];
        const float tf = tanhf(y[src]);
        const float4 xv = *reinterpret_cast<const float4*>(X + (size_t)src * F + lane * 4);
        float4 o = {xv.x * tf, xv.y * tf, xv.z * tf, xv.w * tf};
        *reinterpret_cast<float4*>(outX + (size_t)k * F + lane * 4) = o;
        return;
    }

    // ---- sparse scatter: one kept row per block ----
    const int row  = blockIdx.x;
    const int ridx = idx[row];                    // uniform
    const float* __restrict__ arow = A + (size_t)ridx * N;
    float* __restrict__ orow = outA + (size_t)row * K_KEEP;

    #pragma unroll 4
    for (int it = 0; it < 16; ++it) {
        const int c0 = it * 1024 + t * 4;
        const f32x4 v = __builtin_nontemporal_load(
            reinterpret_cast<const f32x4*>(arow + c0));
        if (v.x != 0.0f || v.y != 0.0f || v.z != 0.0f || v.w != 0.0f) {
            #pragma unroll
            for (int e = 0; e < 4; ++e) {
                const float ve = v[e];
                if (ve != 0.0f) {
                    const unsigned short cr = colrank[c0 + e];
                    if (cr != 0xFFFFu)
                        __builtin_nontemporal_store(ve, orow + cr);
                }
            }
        }
    }
}

// ---------------------------------------------------------------------------
extern "C" void kernel_launch(void* const* d_in, const int* in_sizes, int n_in,
                              void* d_out, int out_size, void* d_ws, size_t ws_size,
                              hipStream_t stream) {
    const float* X = (const float*)d_in[0];  // [N, F]
    const float* A = (const float*)d_in[1];  // [N, N]
    const float* p = (const float*)d_in[2];  // [F, 1]

    float* out  = (float*)d_out;
    float* outX = out;                          // [K_KEEP, F]
    float* outA = out + (size_t)K_KEEP * F;     // [K_KEEP, K_KEEP]

    char* ws = (char*)d_ws;
    float*          y       = (float*)ws;                     // 65536 B
    int*            idx     = (int*)(ws + 65536);             // 32768 B
    unsigned short* colrank = (unsigned short*)(ws + 98304);  // 32768 B

    hipMemsetAsync(outA, 0, (size_t)K_KEEP * K_KEEP * sizeof(float), stream);
    score_kernel<<<N / 4, 256, 0, stream>>>(X, p, y);
    select_emit_kernel<<<1, 1024, 0, stream>>>(y, idx, colrank);
    scatter_kernel<<<K_KEEP + K_KEEP / 4, 256, 0, stream>>>(A, X, y, idx, colrank,
                                                            outX, outA);
}

// Round 14
// 160.572 us; speedup vs baseline: 1.3112x; 1.3112x over previous
//
#include <hip/hip_runtime.h>
#include <math.h>

#define N 16384
#define F 256
#define K_KEEP 8192
#define QS 4096    // columns per apool block (quarter row)
#define APOOL_BLOCKS (K_KEEP * 4)

typedef float f32x4 __attribute__((ext_vector_type(4)));  // native vec for nontemporal builtins

// ---------------------------------------------------------------------------
// Kernel 1: y[i] = dot(X[i,:], p)/||p|| (fp64 accum), stored f32.
// One wave per row; lane l covers 4 consecutive floats.
// ---------------------------------------------------------------------------
__global__ __launch_bounds__(256) void score_kernel(const float* __restrict__ X,
                                                    const float* __restrict__ p,
                                                    float* __restrict__ y) {
    const int wave = threadIdx.x >> 6;
    const int lane = threadIdx.x & 63;
    const int row  = blockIdx.x * 4 + wave;

    const float4 pv = *reinterpret_cast<const float4*>(p + lane * 4);
    const float4 xv = *reinterpret_cast<const float4*>(X + (size_t)row * F + lane * 4);

    double pp = (double)pv.x * pv.x + (double)pv.y * pv.y +
                (double)pv.z * pv.z + (double)pv.w * pv.w;
    double xp = (double)xv.x * pv.x + (double)xv.y * pv.y +
                (double)xv.z * pv.z + (double)xv.w * pv.w;

    #pragma unroll
    for (int off = 32; off >= 1; off >>= 1) {
        pp += __shfl_down(pp, off, 64);
        xp += __shfl_down(xp, off, 64);
    }
    if (lane == 0) y[row] = (float)(xp / sqrt(pp));
}

// ---------------------------------------------------------------------------
// Kernel 2 (single block, 1024 threads): full selection pipeline, y read from
// global EXACTLY ONCE into registers (16 contiguous values per thread).
//   A: register load + uniform value-histogram ([-6,6] x 4096 bins; y~N(0,1)
//      => ~19/bin near median, contention-free).
//   B: 4-bin chunk sums + scan -> boundary bin b* + in-bin rank r.
//   C: register re-scan -> candidates of bin b* -> exact thr.
//   D: per-thread 16-bit kept mask (contiguous ownership) -> LDS.
//   E: first 256 threads assemble u64 words, popcount+scan -> wexcl[256],
//      emit ascending idx[] + in-quarter srcq[].
// ---------------------------------------------------------------------------
__global__ __launch_bounds__(1024) void select_emit_kernel(const float* __restrict__ y,
                                                           int* __restrict__ idx,
                                                           unsigned short* __restrict__ srcq,
                                                           int* __restrict__ wexcl) {
    __shared__ int hist[4096];
    __shared__ int part[1024];
    __shared__ int sc[256];
    __shared__ int bres[2];
    __shared__ float cand[1024];
    __shared__ int ccnt;
    __shared__ float sthr;
    __shared__ unsigned short fbw16[1024];
    const int t = threadIdx.x;

    #pragma unroll
    for (int q = 0; q < 4; ++q) hist[q * 1024 + t] = 0;
    if (t == 0) ccnt = 0;
    __syncthreads();

    // Phase A: one-shot register load of y[t*16 .. t*16+16) + histogram.
    float yv[16];
    const float4* __restrict__ y4 = reinterpret_cast<const float4*>(y + t * 16);
    #pragma unroll
    for (int q = 0; q < 4; ++q) {
        const float4 v = y4[q];
        yv[q * 4 + 0] = v.x; yv[q * 4 + 1] = v.y;
        yv[q * 4 + 2] = v.z; yv[q * 4 + 3] = v.w;
    }
    int bins[16];
    #pragma unroll
    for (int j = 0; j < 16; ++j) {
        const float v = fminf(fmaxf(yv[j] * 341.3333f + 2048.0f, 0.0f), 4095.0f);
        bins[j] = (int)v;
        atomicAdd(&hist[bins[j]], 1);
    }
    __syncthreads();

    // Phase B: chunk sums (4 bins/thread), inclusive scan, locate b*.
    part[t] = hist[t * 4] + hist[t * 4 + 1] + hist[t * 4 + 2] + hist[t * 4 + 3];
    __syncthreads();
    for (int off = 1; off < 1024; off <<= 1) {
        const int v = (t >= off) ? part[t - off] : 0;
        __syncthreads();
        part[t] += v;
        __syncthreads();
    }
    int acc = part[1023] - part[t];    // count strictly above chunk t's top bin
    int fbin = -1, fr = 0;
    #pragma unroll
    for (int q = 3; q >= 0; --q) {
        const int b = t * 4 + q;
        const int h = hist[b];
        if (fbin < 0 && acc <= K_KEEP - 1 && K_KEEP - 1 < acc + h) {
            fbin = b; fr = K_KEEP - acc;   // 1-based rank inside bin
        }
        acc += h;
    }
    if (fbin >= 0) { bres[0] = fbin; bres[1] = fr; }
    __syncthreads();
    const int bstar = bres[0];
    const int r     = bres[1];

    // Phase C: candidates from registers, exact in-bin select -> thr.
    #pragma unroll
    for (int j = 0; j < 16; ++j) {
        if (bins[j] == bstar) {
            const int pos = atomicAdd(&ccnt, 1);
            if (pos < 1024) cand[pos] = yv[j];
        }
    }
    __syncthreads();
    const int cc = (ccnt < 1024) ? ccnt : 1024;
    if (t < cc) {
        const float kk = cand[t];
        int g = 0;
        for (int j = 0; j < cc; ++j) g += (int)(cand[j] > kk);
        if (g == r - 1) sthr = kk;
    }
    __syncthreads();
    const float thr = sthr;

    // Phase D: per-thread contiguous 16-bit kept mask.
    unsigned int mask = 0;
    #pragma unroll
    for (int j = 0; j < 16; ++j) mask |= ((unsigned int)(yv[j] >= thr)) << j;
    fbw16[t] = (unsigned short)mask;
    __syncthreads();

    // Phase E: assemble u64 words, scan, emit.
    unsigned long long m = 0;
    if (t < 256) {
        m = (unsigned long long)fbw16[4 * t]
          | ((unsigned long long)fbw16[4 * t + 1] << 16)
          | ((unsigned long long)fbw16[4 * t + 2] << 32)
          | ((unsigned long long)fbw16[4 * t + 3] << 48);
        sc[t] = __popcll(m);
    }
    __syncthreads();
    for (int off = 1; off < 256; off <<= 1) {
        const int v = (t >= off && t < 256) ? sc[t - off] : 0;
        __syncthreads();
        if (t < 256) sc[t] += v;
        __syncthreads();
    }
    if (t < 256) {
        const int c = __popcll(m);
        int base = sc[t] - c;
        wexcl[t] = base;
        unsigned long long mm = m;
        const int col = t * 64;
        while (mm) {
            const int b = __ffsll((long long)mm) - 1;
            mm &= (mm - 1);
            const int i = col + b;
            idx[base]  = i;
            srcq[base] = (unsigned short)(i & (QS - 1));
            ++base;
        }
    }
}

// ---------------------------------------------------------------------------
// Kernel 3 (fused pool): blocks [0, 32768): A_pooled via LDS-staged quarter
// row + srcq gather + aligned float4 nontemporal stores. Blocks [32768, +2048):
// X_pooled (one wave per kept row).
// ---------------------------------------------------------------------------
__global__ __launch_bounds__(256) void pool_kernel(const float* __restrict__ A,
                                                   const float* __restrict__ X,
                                                   const float* __restrict__ y,
                                                   const int* __restrict__ idx,
                                                   const unsigned short* __restrict__ srcq,
                                                   const int* __restrict__ wexcl,
                                                   float* __restrict__ outX,
                                                   float* __restrict__ outA) {
    const int t = threadIdx.x;

    if (blockIdx.x >= APOOL_BLOCKS) {  // ---- xpool part ----
        const int k    = (blockIdx.x - APOOL_BLOCKS) * 4 + (t >> 6);
        const int lane = t & 63;
        const int src  = idx[k];
        const float tf = tanhf(y[src]);
        const float4 xv = *reinterpret_cast<const float4*>(X + (size_t)src * F + lane * 4);
        float4 o = {xv.x * tf, xv.y * tf, xv.z * tf, xv.w * tf};
        *reinterpret_cast<float4*>(outX + (size_t)k * F + lane * 4) = o;
        return;
    }

    // ---- apool part: one (row, quarter) per block ----
    __shared__ float buf[QS];
    const int row  = blockIdx.x >> 2;
    const int h    = blockIdx.x & 3;
    const int ridx = idx[row];                    // uniform
    const int kb   = wexcl[h * 64];               // uniform
    const int ke   = (h < 3) ? wexcl[h * 64 + 64] : K_KEEP;

    const f32x4* __restrict__ a4 =
        reinterpret_cast<const f32x4*>(A + (size_t)ridx * N + h * QS);
    f32x4* __restrict__ b4 = reinterpret_cast<f32x4*>(buf);
    #pragma unroll
    for (int s = 0; s < 4; ++s) b4[s * 256 + t] = __builtin_nontemporal_load(a4 + s * 256 + t);
    __syncthreads();

    float* __restrict__ orow = outA + (size_t)row * K_KEEP;
    const int k4b = (kb + 3) & ~3;
    const int k4e = ke & ~3;
    if (t < (k4b - kb)) orow[kb + t] = buf[srcq[kb + t]];
    if (t < (ke - k4e)) orow[k4e + t] = buf[srcq[k4e + t]];
    for (int k4 = k4b + 4 * t; k4 < k4e; k4 += 1024) {
        const ushort4 s4 = *reinterpret_cast<const ushort4*>(srcq + k4);
        f32x4 v = {buf[s4.x], buf[s4.y], buf[s4.z], buf[s4.w]};
        __builtin_nontemporal_store(v, reinterpret_cast<f32x4*>(orow + k4));
    }
}

// ---------------------------------------------------------------------------
extern "C" void kernel_launch(void* const* d_in, const int* in_sizes, int n_in,
                              void* d_out, int out_size, void* d_ws, size_t ws_size,
                              hipStream_t stream) {
    const float* X = (const float*)d_in[0];  // [N, F]
    const float* A = (const float*)d_in[1];  // [N, N]
    const float* p = (const float*)d_in[2];  // [F, 1]

    float* out  = (float*)d_out;
    float* outX = out;                          // [K_KEEP, F]
    float* outA = out + (size_t)K_KEEP * F;     // [K_KEEP, K_KEEP]

    char* ws = (char*)d_ws;
    float*          y     = (float*)ws;                     // 65536 B
    int*            wexcl = (int*)(ws + 65536);             // 1024 B
    int*            idx   = (int*)(ws + 66560);             // 32768 B
    unsigned short* srcq  = (unsigned short*)(ws + 99328);  // 16384 B

    score_kernel<<<N / 4, 256, 0, stream>>>(X, p, y);
    select_emit_kernel<<<1, 1024, 0, stream>>>(y, idx, srcq, wexcl);
    pool_kernel<<<APOOL_BLOCKS + K_KEEP / 4, 256, 0, stream>>>(A, X, y, idx, srcq, wexcl,
                                                               outX, outA);
}